// Round 9
// baseline (288.463 us; speedup 1.0000x reference)
//
#include <hip/hip_runtime.h>

// y[b, n*DOUT+o] = sum_i x[b,n,i] * W[n,i,o] + bias[n,o]
// B=2048, N=64, DIN=512, DOUT=512, fp32 in/out, bf16 MFMA (fp32 accum).
// R9: counted-vmcnt pipeline at sane budgets. BM=64 BN=256 BK=32, 256 thr
// (4 waves, 64x64 wave-tile), 43KB LDS -> 3 blocks/CU. Per K-step: raw
// barrier pair, stage B(kt+1) via global_load_lds + A-load(kt+3) 3-deep in
// regs, s_waitcnt vmcnt(8) steady state (never 0 until tail).

#define NN 64
#define DIN 512
#define DOUT 512
#define BM 64
#define BN 256
#define BK 32
#define KSTEPS (DIN / BK)         // 16
#define APITCH 40                 // shorts per A row (80B, 16B-aligned, 2-way-free)
#define ROWSTRIDE (NN * DIN)
#define OUTSTRIDE (NN * DOUT)

typedef __bf16 bf16x8 __attribute__((ext_vector_type(8)));
typedef float f32x4 __attribute__((ext_vector_type(4)));

__device__ __forceinline__ unsigned short f2bf(float f) {
    return __builtin_bit_cast(unsigned short, (__bf16)f);  // RNE
}
__device__ __forceinline__ unsigned int f2bf2(float a, float b) {
    return (unsigned int)f2bf(a) | ((unsigned int)f2bf(b) << 16);
}

typedef const __attribute__((address_space(1))) unsigned int* gas1_t;
typedef __attribute__((address_space(3))) unsigned int* las3_t;
__device__ __forceinline__ void gload_lds16(const void* g, void* l) {
    __builtin_amdgcn_global_load_lds((gas1_t)g, (las3_t)l, 16, 0, 0);
}

#define WAITV(n) asm volatile("s_waitcnt vmcnt(" #n ")" ::: "memory")
#define WAITLGKM asm volatile("s_waitcnt lgkmcnt(0)" ::: "memory")

// ---- pre-pass: Wt[n][o][i] = bf16(W[n][i][o]) ----
__global__ void wt_transpose_kernel(const float* __restrict__ W,
                                    unsigned short* __restrict__ Wt) {
    __shared__ float tile[32][33];
    const int n  = blockIdx.z;
    const int i0 = blockIdx.x * 32;
    const int o0 = blockIdx.y * 32;
    const float* Wn = W + (size_t)n * DIN * DOUT;
    unsigned short* Wtn = Wt + (size_t)n * DIN * DOUT;
    const int tx = threadIdx.x, ty = threadIdx.y;
#pragma unroll
    for (int q = 0; q < 4; ++q)
        tile[ty + q * 8][tx] = Wn[(size_t)(i0 + ty + q * 8) * DOUT + (o0 + tx)];
    __syncthreads();
#pragma unroll
    for (int q = 0; q < 4; ++q)
        Wtn[(size_t)(o0 + ty + q * 8) * DIN + (i0 + tx)] = f2bf(tile[tx][ty + q * 8]);
}

// ---- main GEMM ----
__global__ __launch_bounds__(256, 3) void node_gemm_kernel(
    const float* __restrict__ X, const unsigned short* __restrict__ Wt,
    const float* __restrict__ Bias, float* __restrict__ Out) {
    __shared__ unsigned short As[2][BM * APITCH];   // 2 x 5120 B
    __shared__ unsigned short Bs[2][BN * BK];       // 2 x 16384 B

    // 4096 WGs. node -> XCD affinity: node n lives on XCD n&7, so each node's
    // 64 blocks (32 mtiles x 2 ntiles) are co-resident -> W panel L2-hot.
    const int bid  = blockIdx.x;
    const int xcd  = bid & 7;
    const int seq  = bid >> 3;            // 0..511
    const int node = (seq >> 6) * 8 + xcd;
    const int rem  = seq & 63;
    const int mtile = rem >> 1;
    const int ntile = rem & 1;
    const int brow = mtile * BM;
    const int bcol = ntile * BN;

    const int tid  = threadIdx.x;
    const int lane = tid & 63;
    const int w    = tid >> 6;        // wave 0..3, owns cols 64w..64w+63

    const float* Xb = X + (size_t)brow * ROWSTRIDE + node * DIN;
    const unsigned short* Wb = Wt + (size_t)node * DIN * DOUT + (size_t)bcol * DIN;

    // A staging: thread t -> row t>>2 (0..63), kq t&3 (8 floats -> 16B bf16)
    const int a_row = tid >> 2;
    const int a_kq  = tid & 3;
    const float* a_src = Xb + (size_t)a_row * ROWSTRIDE + a_kq * 8;
    const int a_dst = a_row * APITCH + a_kq * 8;   // shorts; byte=row*80+kq*16

    // B staging via gload_lds: inst i = q*4+w covers B-cols 16i..16i+15
    const unsigned short* b_src[4];
    int b_dst[4];
#pragma unroll
    for (int q = 0; q < 4; ++q) {
        const int i = q * 4 + w;
        const int c = i * 16 + (lane >> 2);
        const int s = lane & 3;
        const int gs = s ^ ((c >> 1) & 3);       // inverse slot swizzle on source
        b_src[q] = Wb + (size_t)c * DIN + gs * 8;
        b_dst[q] = i * 512;                      // shorts (1KB per inst)
    }

    // fragment read offsets
    const int arow = lane & 15;
    const int akk  = lane >> 4;
    const int afrag = arow * APITCH + akk * 8;                 // + m*16*APITCH
    const int bswz  = akk;  // per-col swizzle applied below
    (void)bswz;

    f32x4 acc[4][4] = {};
    float4 av[3][2];   // 3-deep A register prefetch

    auto stageB = [&](int buf, int kt) {
#pragma unroll
        for (int q = 0; q < 4; ++q)
            gload_lds16(b_src[q] + kt * BK, &Bs[buf][b_dst[q]]);
    };
    auto loadA = [&](int kt, int set) {
        const float* p = a_src + kt * BK;
        av[set][0] = *reinterpret_cast<const float4*>(p);
        av[set][1] = *reinterpret_cast<const float4*>(p + 4);
    };
    auto storeA = [&](int buf, int set) {
        uint4 pk;
        pk.x = f2bf2(av[set][0].x, av[set][0].y);
        pk.y = f2bf2(av[set][0].z, av[set][0].w);
        pk.z = f2bf2(av[set][1].x, av[set][1].y);
        pk.w = f2bf2(av[set][1].z, av[set][1].w);
        *reinterpret_cast<uint4*>(&As[buf][a_dst]) = pk;
    };
    auto compute = [&](int buf) {
        bf16x8 af[4], bq[4];
#pragma unroll
        for (int m = 0; m < 4; ++m)
            af[m] = *reinterpret_cast<const bf16x8*>(&As[buf][afrag + m * 16 * APITCH]);
#pragma unroll
        for (int n = 0; n < 4; ++n) {
            const int col = w * 64 + n * 16 + arow;
            const int ks  = akk ^ ((col >> 1) & 3);
            bq[n] = *reinterpret_cast<const bf16x8*>(&Bs[buf][col * BK + ks * 8]);
        }
#pragma unroll
        for (int m = 0; m < 4; ++m)
#pragma unroll
            for (int n = 0; n < 4; ++n)
                acc[m][n] = __builtin_amdgcn_mfma_f32_16x16x32_bf16(af[m], bq[n], acc[m][n], 0, 0, 0);
    };

    // ---- prologue: A(0..2) in regs, B(0) staged; one-time full drain.
    loadA(0, 0);
    loadA(1, 1);
    loadA(2, 2);
    stageB(0, 0);
    WAITV(0);
    storeA(0, 0);
    WAITLGKM;
    __builtin_amdgcn_s_barrier();

    // ---- main loop (fully unrolled). vmcnt ledger (per wave, verified):
    // steady queue after wait = [A(kt+2)x2, B(kt+1)x4, A(kt+3)x2] = 8.
#pragma unroll
    for (int kt = 0; kt < KSTEPS; ++kt) {
        WAITLGKM;                         // my iter-(kt-1) LDS reads/writes retired
        __builtin_amdgcn_s_barrier();     // all waves done -> WAR-safe to restage
        __builtin_amdgcn_sched_barrier(0);
        if (kt + 1 < KSTEPS) stageB((kt + 1) & 1, kt + 1);
        if (kt + 3 < KSTEPS) loadA(kt + 3, (kt + 3) % 3);
        __builtin_amdgcn_sched_barrier(0);
        if (kt <= KSTEPS - 4)      WAITV(8);   // drain B(kt)+A(kt+1), keep 8 flying
        else if (kt == KSTEPS - 3) WAITV(6);
        else if (kt == KSTEPS - 2) WAITV(4);
        else                       WAITV(0);
        __builtin_amdgcn_s_barrier();     // everyone's B(kt) portions landed
        __builtin_amdgcn_sched_barrier(0);
        if (kt + 1 < KSTEPS) storeA((kt + 1) & 1, (kt + 1) % 3);
        compute(kt & 1);
    }

    // ---- epilogue: D mapping col = lane&15, row = (lane>>4)*4 + j
    const float* bn = Bias + node * DOUT + bcol;
    float* outb = Out + (size_t)brow * OUTSTRIDE + node * DOUT + bcol;
#pragma unroll
    for (int n = 0; n < 4; ++n) {
        const int col = w * 64 + n * 16 + arow;
        const float bias = bn[col];
#pragma unroll
        for (int m = 0; m < 4; ++m) {
            const int r0 = m * 16 + akk * 4;
#pragma unroll
            for (int j = 0; j < 4; ++j)
                outb[(size_t)(r0 + j) * OUTSTRIDE + col] = acc[m][n][j] + bias;
        }
    }
}

extern "C" void kernel_launch(void* const* d_in, const int* in_sizes, int n_in,
                              void* d_out, int out_size, void* d_ws, size_t ws_size,
                              hipStream_t stream) {
    const float* x = (const float*)d_in[0];      // [2048, 64, 512]
    const float* W = (const float*)d_in[1];      // [64, 512, 512]
    const float* b = (const float*)d_in[2];      // [64, 512]
    float* out = (float*)d_out;                  // [2048, 64*512]
    unsigned short* Wt = (unsigned short*)d_ws;  // bf16 [64][512][512] = 33.5 MB

    wt_transpose_kernel<<<dim3(DIN / 32, DOUT / 32, NN), dim3(32, 8), 0, stream>>>(W, Wt);
    node_gemm_kernel<<<dim3(4096), dim3(256), 0, stream>>>(x, Wt, b, out);
}